// Round 6
// baseline (625.565 us; speedup 1.0000x reference)
//
#include <hip/hip_runtime.h>
#include <math.h>

#define N_NODES 10000
#define E_EDGES 160000
#define HID     128
#define HOUT    512      // HEADS*HID
#define NEG_S   0.2f

#define RL(v_, l_) __builtin_amdgcn_readlane((v_), (l_))

// ---------------------------------------------------------------- init / CSR
__global__ void k_zero(int* __restrict__ deg) {
  int i = blockIdx.x * 256 + threadIdx.x;
  if (i < N_NODES) deg[i] = 0;
}

__global__ void k_deg(const int* __restrict__ dst, int* __restrict__ deg) {
  int e = blockIdx.x * 256 + threadIdx.x;
  if (e >= E_EDGES) return;
  atomicAdd(&deg[dst[e]], 1);
}

__global__ __launch_bounds__(1024) void k_scan(const int* __restrict__ deg, int* __restrict__ row_ptr) {
  __shared__ int buf[1024];
  int carry = 0;
  if (threadIdx.x == 0) row_ptr[0] = 0;
  for (int base = 0; base < N_NODES; base += 1024) {
    int i = base + (int)threadIdx.x;
    int val = (i < N_NODES) ? (deg[i] + 1) : 0;   // +1 slot for self loop
    buf[threadIdx.x] = val;
    __syncthreads();
    for (int off = 1; off < 1024; off <<= 1) {
      int t = (threadIdx.x >= (unsigned)off) ? buf[threadIdx.x - off] : 0;
      __syncthreads();
      buf[threadIdx.x] += t;
      __syncthreads();
    }
    if (i < N_NODES) row_ptr[i + 1] = carry + buf[threadIdx.x];
    carry += buf[1023];
    __syncthreads();
  }
}

__global__ void k_csr_init(const int* __restrict__ row_ptr, int* __restrict__ cursor,
                           int* __restrict__ csr_eid) {
  int v = blockIdx.x * 256 + threadIdx.x;
  if (v >= N_NODES) return;
  cursor[v] = 1;                       // slot 0 reserved (self loop, unused by k_fused)
  csr_eid[row_ptr[v]] = E_EDGES + v;
}

__global__ void k_csr_scatter(const int* __restrict__ dst, const int* __restrict__ row_ptr,
                              int* __restrict__ cursor, int* __restrict__ csr_eid) {
  int e = blockIdx.x * 256 + threadIdx.x;
  if (e >= E_EDGES) return;
  int v = dst[e];
  int pos = row_ptr[v] + atomicAdd(&cursor[v], 1);
  csr_eid[pos] = e;
}

// ------------------------------------------------------------- node embedding
__global__ __launch_bounds__(128) void k_node_emb(const float* __restrict__ x,
                                                  const float* __restrict__ W,
                                                  const float* __restrict__ b,
                                                  float* __restrict__ h) {
  __shared__ float sx[64];
  int n = blockIdx.x;
  int c = threadIdx.x;
  if (c < 64) sx[c] = x[(size_t)n * 64 + c];
  __syncthreads();
  float acc = b[c];
#pragma unroll
  for (int k = 0; k < 64; ++k) acc = fmaf(sx[k], W[k * HID + c], acc);
  h[(size_t)n * HID + c] = acc;
}

// --------------------------------------------- per-layer weight prep: C = edge_W@We, d = edge_b@We
__global__ __launch_bounds__(512) void k_prep(const float* __restrict__ edge_W,
                                              const float* __restrict__ edge_b,
                                              const float* __restrict__ We,
                                              float* __restrict__ C_all,
                                              float* __restrict__ d_all) {
  int i = blockIdx.x;   // 0..16 (16 == edge_b row)
  int l = blockIdx.y;
  int j = threadIdx.x;
  const float* wrow = (i < 16) ? (edge_W + i * HID) : edge_b;
  const float* wel = We + (size_t)l * HID * HOUT;
  float acc = 0.f;
  for (int k = 0; k < HID; ++k) acc = fmaf(wrow[k], wel[(size_t)k * HOUT + j], acc);
  if (i < 16) C_all[(size_t)l * 16 * HOUT + (size_t)i * HOUT + j] = acc;
  else        d_all[(size_t)l * HOUT + j] = acc;
}

// ------------------------------------------------------------- xl/xr GEMM
// B-resident streaming GEMM: Bs[128][64] loaded once; A streamed in 64-row
// chunks (transposed+swizzled into As). 512 blocks = 2/CU so load/compute
// overlap across blocks. grid (32 rowblocks, 8 coltiles, 2 lr), 256 thr.
__global__ __launch_bounds__(256) void k_gemm_xlr(
    const float* __restrict__ A,
    const float* __restrict__ Wl, const float* __restrict__ bl,
    const float* __restrict__ Wr, const float* __restrict__ br,
    float* __restrict__ xl, float* __restrict__ xr) {
  const float* B = blockIdx.z ? Wr : Wl;
  const float* bias = blockIdx.z ? br : bl;
  float* out = blockIdx.z ? xr : xl;
  __shared__ float Bs[128][64];
  __shared__ float As[128][64];   // [k][row], XOR-swizzled rows
  const int tid = threadIdx.x;
  const int bn = blockIdx.y << 6;

  // load B panel once: 128 k x 64 n
#pragma unroll
  for (int i = 0; i < 8; ++i) {
    int linear = tid + (i << 8);
    int kr = linear >> 4;
    int cq = (linear & 15) << 2;
    *(float4*)(&Bs[kr][cq]) = *(const float4*)(B + (size_t)kr * HOUT + bn + cq);
  }

  const int tr = tid >> 4;     // 0..15 -> 4 rows each
  const int tc = tid & 15;     // 0..15 -> 4 cols each
  float4 bv = *(const float4*)(bias + bn + (tc << 2));

  for (int ch = 0; ch < 5; ++ch) {
    int rbase = blockIdx.x * 320 + (ch << 6);
    __syncthreads();           // As safe to overwrite (and Bs ready on ch=0)
#pragma unroll
    for (int i = 0; i < 8; ++i) {
      int linear = tid + (i << 8);
      int kq = linear & 31;          // float4 index along k
      int r  = linear >> 5;          // 0..63
      int grow = rbase + r;
      float4 av = (grow < N_NODES) ? *(const float4*)(A + (size_t)grow * HID + (kq << 2))
                                   : make_float4(0.f, 0.f, 0.f, 0.f);
      int kk = kq << 2;
      int rc = r ^ ((kq & 7) << 2);  // swizzle kills 32-way write conflict
      As[kk + 0][rc] = av.x; As[kk + 1][rc] = av.y;
      As[kk + 2][rc] = av.z; As[kk + 3][rc] = av.w;
    }
    __syncthreads();

    float acc[4][4] = {};
#pragma unroll 16
    for (int k = 0; k < HID; ++k) {
      int f = ((k >> 2) & 7) << 2;
      float4 a = *(const float4*)(&As[k][(tr << 2) ^ f]);
      float4 b = *(const float4*)(&Bs[k][tc << 2]);
      acc[0][0] = fmaf(a.x, b.x, acc[0][0]); acc[0][1] = fmaf(a.x, b.y, acc[0][1]);
      acc[0][2] = fmaf(a.x, b.z, acc[0][2]); acc[0][3] = fmaf(a.x, b.w, acc[0][3]);
      acc[1][0] = fmaf(a.y, b.x, acc[1][0]); acc[1][1] = fmaf(a.y, b.y, acc[1][1]);
      acc[1][2] = fmaf(a.y, b.z, acc[1][2]); acc[1][3] = fmaf(a.y, b.w, acc[1][3]);
      acc[2][0] = fmaf(a.z, b.x, acc[2][0]); acc[2][1] = fmaf(a.z, b.y, acc[2][1]);
      acc[2][2] = fmaf(a.z, b.z, acc[2][2]); acc[2][3] = fmaf(a.z, b.w, acc[2][3]);
      acc[3][0] = fmaf(a.w, b.x, acc[3][0]); acc[3][1] = fmaf(a.w, b.y, acc[3][1]);
      acc[3][2] = fmaf(a.w, b.z, acc[3][2]); acc[3][3] = fmaf(a.w, b.w, acc[3][3]);
    }
#pragma unroll
    for (int i = 0; i < 4; ++i) {
      int grow = rbase + (tr << 2) + i;
      if (grow < N_NODES) {
        float4 sv;
        sv.x = acc[i][0] + bv.x; sv.y = acc[i][1] + bv.y;
        sv.z = acc[i][2] + bv.z; sv.w = acc[i][3] + bv.w;
        *(float4*)(out + (size_t)grow * HOUT + bn + (tc << 2)) = sv;
      }
    }
  }
}

// ------------------------------------------------- fused logits+softmax+aggregate
// One wave per node; online softmax; C (16x512) in LDS; pipelined index chain.
__device__ __forceinline__ float edge_logit(
    float4 e0, float4 e1, float4 xa, float4 xb, float4 av0, float4 av1) {
  float t, p;
  t = e0.x + xa.x; t = fmaxf(t, NEG_S * t); p  = t * av0.x;
  t = e0.y + xa.y; t = fmaxf(t, NEG_S * t); p += t * av0.y;
  t = e0.z + xa.z; t = fmaxf(t, NEG_S * t); p += t * av0.z;
  t = e0.w + xa.w; t = fmaxf(t, NEG_S * t); p += t * av0.w;
  t = e1.x + xb.x; t = fmaxf(t, NEG_S * t); p += t * av1.x;
  t = e1.y + xb.y; t = fmaxf(t, NEG_S * t); p += t * av1.y;
  t = e1.z + xb.z; t = fmaxf(t, NEG_S * t); p += t * av1.z;
  t = e1.w + xb.w; t = fmaxf(t, NEG_S * t); p += t * av1.w;
#pragma unroll
  for (int off = 1; off <= 8; off <<= 1) p += __shfl_xor(p, off);  // per-head (16-lane) sum
  return p;
}

#define EEACC(q, c0, c1, A, B) \
  A.x = fmaf(q, c0.x, A.x); A.y = fmaf(q, c0.y, A.y); \
  A.z = fmaf(q, c0.z, A.z); A.w = fmaf(q, c0.w, A.w); \
  B.x = fmaf(q, c1.x, B.x); B.y = fmaf(q, c1.y, B.y); \
  B.z = fmaf(q, c1.z, B.z); B.w = fmaf(q, c1.w, B.w);

__global__ __launch_bounds__(512) void k_fused(
    const float* __restrict__ xl, const float* __restrict__ xr,
    const float* __restrict__ edge_attr, const int* __restrict__ src,
    const int* __restrict__ row_ptr, const int* __restrict__ csr_eid,
    const float* __restrict__ C, const float* __restrict__ dvec,
    const float* __restrict__ att, const float* __restrict__ bias,
    float* __restrict__ hout) {
  __shared__ float Cs[16 * 512];
  const int tid = threadIdx.x;
#pragma unroll
  for (int i = 0; i < 4; ++i)
    *(float4*)(&Cs[i * 2048 + tid * 4]) = *(const float4*)(C + i * 2048 + tid * 4);
  __syncthreads();

  const int wid = tid >> 6, lane = tid & 63;
  const int v = blockIdx.x * 8 + wid;
  if (v >= N_NODES) return;
  const int r0 = row_ptr[v], r1 = row_ptr[v + 1];
  const int cnt = r1 - r0 - 1;          // real incoming edges
  const int kk = lane & 15, slot = lane >> 4;
  const int cb = lane * 8;              // my 8-channel base (head = lane>>4)

  float4 av0 = *(const float4*)(att + cb),  av1 = *(const float4*)(att + cb + 4);
  // base = xr + (cnt>0 ? dvec : 0): folds the lin_edge bias term and the
  // target transform into the ee accumulator init (used by edges AND self loop).
  float4 base0 = *(const float4*)(xr + (size_t)v * HOUT + cb);
  float4 base1 = *(const float4*)(xr + (size_t)v * HOUT + cb + 4);
  if (cnt > 0) {
    float4 dv0 = *(const float4*)(dvec + cb), dv1 = *(const float4*)(dvec + cb + 4);
    base0.x += dv0.x; base0.y += dv0.y; base0.z += dv0.z; base0.w += dv0.w;
    base1.x += dv1.x; base1.y += dv1.y; base1.z += dv1.z; base1.w += dv1.w;
  }

  float o0=0,o1=0,o2=0,o3=0,o4=0,o5=0,o6=0,o7=0;
  float m = -1e30f, s = 0.f, psum = 0.f;

  // prologue: group-0 index/attr chain
  int sv = 0; float ea = 0.f;
  if (cnt > 0) {
    int idx = slot;
    bool valL = idx < cnt;
    int pos = r0 + 1 + (valL ? idx : 0);
    int eid = csr_eid[pos];
    sv = src[eid];
    ea = valL ? edge_attr[(size_t)eid * 16 + kk] : 0.f;
  }

  for (int g = 0; g < cnt; g += 4) {
    int sv0 = RL(sv, 0), sv1 = RL(sv, 16), sv2 = RL(sv, 32), sv3 = RL(sv, 48);
    const float4* xp0 = (const float4*)(xl + (size_t)sv0 * HOUT + cb);
    const float4* xp1 = (const float4*)(xl + (size_t)sv1 * HOUT + cb);
    const float4* xp2 = (const float4*)(xl + (size_t)sv2 * HOUT + cb);
    const float4* xp3 = (const float4*)(xl + (size_t)sv3 * HOUT + cb);
    float4 xa0 = xp0[0], xb0 = xp0[1];
    float4 xa1 = xp1[0], xb1 = xp1[1];
    float4 xa2 = xp2[0], xb2 = xp2[1];
    float4 xa3 = xp3[0], xb3 = xp3[1];
    psum += ea;
    unsigned eau = __float_as_uint(ea);

    // prefetch next group's chain: hides csr_eid->src->edge_attr latency
    // under the EEACC compute below.
    int nsv = 0; float nea = 0.f;
    if (g + 4 < cnt) {
      int idx = g + 4 + slot;
      bool valL = idx < cnt;
      int pos = r0 + 1 + (valL ? idx : 0);
      int eid = csr_eid[pos];
      nsv = src[eid];
      nea = valL ? edge_attr[(size_t)eid * 16 + kk] : 0.f;
    }

    float4 eA0 = base0, eB0 = base1, eA1 = base0, eB1 = base1;
    float4 eA2 = base0, eB2 = base1, eA3 = base0, eB3 = base1;
#pragma unroll
    for (int k = 0; k < 16; ++k) {
      float4 c0 = *(const float4*)(&Cs[k * 512 + cb]);
      float4 c1 = *(const float4*)(&Cs[k * 512 + cb + 4]);
      float q0 = __uint_as_float(RL(eau, k));
      float q1 = __uint_as_float(RL(eau, 16 + k));
      float q2 = __uint_as_float(RL(eau, 32 + k));
      float q3 = __uint_as_float(RL(eau, 48 + k));
      EEACC(q0, c0, c1, eA0, eB0)
      EEACC(q1, c0, c1, eA1, eB1)
      EEACC(q2, c0, c1, eA2, eB2)
      EEACC(q3, c0, c1, eA3, eB3)
    }

    float lg0 = edge_logit(eA0, eB0, xa0, xb0, av0, av1);
    float lg1 = edge_logit(eA1, eB1, xa1, xb1, av0, av1);
    float lg2 = edge_logit(eA2, eB2, xa2, xb2, av0, av1);
    float lg3 = edge_logit(eA3, eB3, xa3, xb3, av0, av1);
    if (g + 1 >= cnt) lg1 = -1e30f;
    if (g + 2 >= cnt) lg2 = -1e30f;
    if (g + 3 >= cnt) lg3 = -1e30f;

    float gm = fmaxf(fmaxf(lg0, lg1), fmaxf(lg2, lg3));
    float mn = fmaxf(m, gm);
    float sc = __expf(m - mn);
    float p0 = __expf(lg0 - mn), p1 = __expf(lg1 - mn);
    float p2 = __expf(lg2 - mn), p3 = __expf(lg3 - mn);
    m = mn;
    s = s * sc + (p0 + p1) + (p2 + p3);
    o0 = o0*sc + p0*xa0.x + p1*xa1.x + p2*xa2.x + p3*xa3.x;
    o1 = o1*sc + p0*xa0.y + p1*xa1.y + p2*xa2.y + p3*xa3.y;
    o2 = o2*sc + p0*xa0.z + p1*xa1.z + p2*xa2.z + p3*xa3.z;
    o3 = o3*sc + p0*xa0.w + p1*xa1.w + p2*xa2.w + p3*xa3.w;
    o4 = o4*sc + p0*xb0.x + p1*xb1.x + p2*xb2.x + p3*xb3.x;
    o5 = o5*sc + p0*xb0.y + p1*xb1.y + p2*xb2.y + p3*xb3.y;
    o6 = o6*sc + p0*xb0.z + p1*xb1.z + p2*xb2.z + p3*xb3.z;
    o7 = o7*sc + p0*xb0.w + p1*xb1.w + p2*xb2.w + p3*xb3.w;

    sv = nsv; ea = nea;
  }

  // ---- self loop: attr = mean of incoming edge_attr (0 if cnt==0; base handles dvec)
  psum += __shfl_xor(psum, 16);
  psum += __shfl_xor(psum, 32);
  float invd = (cnt > 0) ? (1.f / (float)cnt) : 0.f;
  float mea = psum * invd;
  float4 sA = base0, sB = base1;
  unsigned mu = __float_as_uint(mea);
#pragma unroll
  for (int k = 0; k < 16; ++k) {
    float4 c0 = *(const float4*)(&Cs[k * 512 + cb]);
    float4 c1 = *(const float4*)(&Cs[k * 512 + cb + 4]);
    float q = __uint_as_float(RL(mu, k));
    EEACC(q, c0, c1, sA, sB)
  }
  const float4* xsp = (const float4*)(xl + (size_t)v * HOUT + cb);
  float4 xsa = xsp[0], xsb = xsp[1];
  float lgS = edge_logit(sA, sB, xsa, xsb, av0, av1);
  {
    float mn = fmaxf(m, lgS);
    float sc = __expf(m - mn);
    float pS = __expf(lgS - mn);
    m = mn;
    s = s * sc + pS;
    o0 = o0*sc + pS*xsa.x; o1 = o1*sc + pS*xsa.y;
    o2 = o2*sc + pS*xsa.z; o3 = o3*sc + pS*xsa.w;
    o4 = o4*sc + pS*xsb.x; o5 = o5*sc + pS*xsb.y;
    o6 = o6*sc + pS*xsb.z; o7 = o7*sc + pS*xsb.w;
  }

  // ---- normalize, head-mean, bias, relu, store
  float inv_s = 1.f / s;
  float r[8] = {o0*inv_s, o1*inv_s, o2*inv_s, o3*inv_s,
                o4*inv_s, o5*inv_s, o6*inv_s, o7*inv_s};
#pragma unroll
  for (int j = 0; j < 8; ++j) {
    float t = r[j];
    t += __shfl_xor(t, 16);
    t += __shfl_xor(t, 32);
    r[j] = t * 0.25f;
  }
  if (lane < 16) {
    float4 w0, w1;
    w0.x = fmaxf(r[0] + bias[cb + 0], 0.f); w0.y = fmaxf(r[1] + bias[cb + 1], 0.f);
    w0.z = fmaxf(r[2] + bias[cb + 2], 0.f); w0.w = fmaxf(r[3] + bias[cb + 3], 0.f);
    w1.x = fmaxf(r[4] + bias[cb + 4], 0.f); w1.y = fmaxf(r[5] + bias[cb + 5], 0.f);
    w1.z = fmaxf(r[6] + bias[cb + 6], 0.f); w1.w = fmaxf(r[7] + bias[cb + 7], 0.f);
    *(float4*)(hout + (size_t)v * HID + cb) = w0;
    *(float4*)(hout + (size_t)v * HID + cb + 4) = w1;
  }
}

// ---------------------------------------------------------------- launch
extern "C" void kernel_launch(void* const* d_in, const int* in_sizes, int n_in,
                              void* d_out, int out_size, void* d_ws, size_t ws_size,
                              hipStream_t stream) {
  const float* x         = (const float*)d_in[0];
  const int*   ei        = (const int*)d_in[1];
  const float* edge_attr = (const float*)d_in[2];
  const float* node_W    = (const float*)d_in[3];
  const float* node_b    = (const float*)d_in[4];
  const float* edge_W    = (const float*)d_in[5];
  const float* edge_b    = (const float*)d_in[6];
  const float* Wl        = (const float*)d_in[7];
  const float* bl        = (const float*)d_in[8];
  const float* Wr        = (const float*)d_in[9];
  const float* br        = (const float*)d_in[10];
  const float* We        = (const float*)d_in[11];
  const float* att       = (const float*)d_in[12];
  const float* bias      = (const float*)d_in[13];
  float* out = (float*)d_out;
  const int* src = ei;
  const int* dst = ei + E_EDGES;

  char* p = (char*)d_ws;
  auto alloc = [&](size_t bytes) { char* r = p; p += (bytes + 255) & ~(size_t)255; return r; };
  float* h_a     = (float*)alloc((size_t)N_NODES * HID * 4);
  float* h_b     = (float*)alloc((size_t)N_NODES * HID * 4);
  float* xl      = (float*)alloc((size_t)N_NODES * HOUT * 4);
  float* xr      = (float*)alloc((size_t)N_NODES * HOUT * 4);
  float* C_all   = (float*)alloc((size_t)3 * 16 * HOUT * 4);
  float* d_all   = (float*)alloc((size_t)3 * HOUT * 4);
  int* deg       = (int*)alloc((size_t)N_NODES * 4);
  int* row_ptr   = (int*)alloc((size_t)(N_NODES + 1) * 4);
  int* cursor    = (int*)alloc((size_t)N_NODES * 4);
  int* csr_eid   = (int*)alloc((size_t)(E_EDGES + N_NODES) * 4);

  // preprocessing
  k_zero<<<(N_NODES + 255) / 256, 256, 0, stream>>>(deg);
  k_deg<<<(E_EDGES + 255) / 256, 256, 0, stream>>>(dst, deg);
  k_scan<<<1, 1024, 0, stream>>>(deg, row_ptr);
  k_csr_init<<<(N_NODES + 255) / 256, 256, 0, stream>>>(row_ptr, cursor, csr_eid);
  k_csr_scatter<<<(E_EDGES + 255) / 256, 256, 0, stream>>>(dst, row_ptr, cursor, csr_eid);
  k_node_emb<<<N_NODES, 128, 0, stream>>>(x, node_W, node_b, h_a);
  k_prep<<<dim3(17, 3), 512, 0, stream>>>(edge_W, edge_b, We, C_all, d_all);

  for (int l = 0; l < 3; ++l) {
    const float* hin = (l == 0) ? h_a : ((l == 1) ? h_b : h_a);
    float* hout = (l == 0) ? h_b : ((l == 1) ? h_a : out);
    k_gemm_xlr<<<dim3(32, 8, 2), 256, 0, stream>>>(
        hin, Wl + (size_t)l * HID * HOUT, bl + (size_t)l * HOUT,
        Wr + (size_t)l * HID * HOUT, br + (size_t)l * HOUT, xl, xr);
    k_fused<<<(N_NODES + 7) / 8, 512, 0, stream>>>(
        xl, xr, edge_attr, src, row_ptr, csr_eid,
        C_all + (size_t)l * 16 * HOUT, d_all + (size_t)l * HOUT,
        att + (size_t)l * HOUT, bias + (size_t)l * HID, hout);
  }
}